// Round 1
// baseline (170.715 us; speedup 1.0000x reference)
//
#include <hip/hip_runtime.h>
#include <stdint.h>

// Problem constants
//  B = 32768 samples, T_X = 4, K = 128, 64 groups x 512, out = (64,128,1,1024) fp32
typedef __attribute__((ext_vector_type(8))) short bf16x8;  // 8 bf16 in 4 VGPRs
typedef __attribute__((ext_vector_type(4))) float f32x4;

__device__ __forceinline__ unsigned short f2bf(float x) {
    union { float f; uint32_t u; } v; v.f = x;
    uint32_t r = v.u + 0x7FFFu + ((v.u >> 16) & 1u);   // RNE
    return (unsigned short)(r >> 16);
}
__device__ __forceinline__ uint32_t pack2bf(float a, float b) {
    return (uint32_t)f2bf(a) | ((uint32_t)f2bf(b) << 16);
}
__device__ __forceinline__ float bf2f(uint32_t lo) {
    union { uint32_t u; float f; } v; v.u = lo << 16; return v.f;
}
__device__ __forceinline__ float lrelu(float v) { return v > 0.f ? v : 0.01f * v; }

// ---------------------------------------------------------------------------
// K0: precompute (LDS-tiled small GEMMs, coalesced staging) — unchanged
//   G (split hi/lo bf16): G[i][j] = (1/sqrt(128)) * sum_o Wk[o,i]*Wq[o,j]
//   M (single bf16 RNE):  M[o][c] = inv_sqrt2 * sum_k conv_w[o,(c>>7)*128+k]*Wv[k,c&127]
//   blocks 0..63: G 16x16 tiles; 64..191: M 16x16 tiles; 192: BN constants
// ---------------------------------------------------------------------------
__global__ __launch_bounds__(256) void precompute_kernel(
    const float* __restrict__ Wq, const float* __restrict__ Wk,
    const float* __restrict__ Wv, const float* __restrict__ conv_w,
    const float* __restrict__ conv_b, const float* __restrict__ bn_gamma,
    const float* __restrict__ bn_beta, const float* __restrict__ bn_mean,
    const float* __restrict__ bn_var,
    unsigned short* __restrict__ Gh, unsigned short* __restrict__ Gl,
    unsigned short* __restrict__ Mh,
    float* __restrict__ scale2, float* __restrict__ bias2)
{
    __shared__ float lds0[2176];   // 128x16 pad17 (8704 B) or 16x128 pad132
    __shared__ float lds1[2176];   // 128x16 pad17
    const int tid = threadIdx.x;
    const int bid = blockIdx.x;

    if (bid == 192) {                              // constants
        if (tid < 128) {
            float sc = bn_gamma[tid] * rsqrtf(bn_var[tid] + 1e-5f);
            scale2[tid] = sc;
            bias2[tid]  = (conv_b[tid] - bn_mean[tid]) * sc + bn_beta[tid];
        }
        return;
    }

    if (bid < 64) {                                // ---- G tile (i0, j0)
        int i0 = (bid >> 3) << 4, j0 = (bid & 7) << 4;
        #pragma unroll
        for (int t = 0; t < 8; ++t) {              // stage col-tiles, 64B lines
            int e = tid + t * 256;
            int o = e >> 4, c = e & 15;
            lds0[o * 17 + c] = Wk[o * 128 + i0 + c];
            lds1[o * 17 + c] = Wq[o * 128 + j0 + c];
        }
        __syncthreads();
        int ti = tid >> 4, tj = tid & 15;
        float sum = 0.f;
        #pragma unroll 8
        for (int o = 0; o < 128; ++o) sum += lds0[o * 17 + ti] * lds1[o * 17 + tj];
        float val = sum * 0.08838834764831845f;    // 1/sqrt(128)
        unsigned short h = f2bf(val);
        int idx = (i0 + ti) * 128 + j0 + tj;
        Gh[idx] = h;
        Gl[idx] = f2bf(val - bf2f(h));
    } else {                                       // ---- M tile (o0, c0)
        int rel = bid - 64;
        int o0 = (rel >> 4) << 4, c0 = (rel & 15) << 4;
        int cw0 = (c0 >> 7) << 7, cc0 = c0 & 127;
        #pragma unroll
        for (int t = 0; t < 8; ++t) {
            int e = tid + t * 256;
            int to = e >> 7, k = e & 127;          // conv_w rows: contiguous
            lds0[to * 132 + k] = conv_w[(o0 + to) * 256 + cw0 + k];
            int kk = e >> 4, c = e & 15;           // Wv col-tile
            lds1[kk * 17 + c] = Wv[kk * 128 + cc0 + c];
        }
        __syncthreads();
        int to = tid >> 4, tc = tid & 15;
        float sum = 0.f;
        #pragma unroll 8
        for (int k = 0; k < 128; ++k) sum += lds0[to * 132 + k] * lds1[k * 17 + tc];
        Mh[(o0 + to) * 256 + c0 + tc] = f2bf(sum * 0.7071067811865476f);
    }
}

// ---------------------------------------------------------------------------
// K1: fused attention + IDWT + conv + BN + LeakyReLU.
// r7 changes vs r6: tile halved to 16 samples/block -> 2048 blocks, 16 KB LDS,
// __launch_bounds__(256,8) (VGPR<=64). 8 resident blocks/CU (32 waves = 100%
// occupancy) instead of 4 -> independent blocks interleave across barriers,
// hiding global-load latency (kernel was latency-bound: Mfma 6.5%, VALU 14%,
// HBM 22%, all idle).
// LDS overlays (re-derived for 16-row geometry):
//   [0,8K)   phase0: y bf16 hi [0,4K) + lo [4K,8K)  ->  phase1+: U-low bf16 (32 rows)
//   [8K,16K) phase0b out: gbuf fp32 (16 x 128)      ->  phase1+: U-high bf16
// U-high row pair 2*b_loc,2*b_loc+1 lands exactly on the gbuf row b_loc the
// same thread just consumed (same-wave read-before-write => no hazard).
// ---------------------------------------------------------------------------
#define AADDR(row, gi)   (((row) << 8) + ((((gi) ^ ((row) & 7))) << 4))

__global__ __launch_bounds__(256, 8) void fused_kernel(
    const float* __restrict__ x, const float* __restrict__ y,
    const unsigned short* __restrict__ Gh, const unsigned short* __restrict__ Gl,
    const unsigned short* __restrict__ Mh,
    const float* __restrict__ scale2, const float* __restrict__ bias2,
    float* __restrict__ out)
{
    __shared__ __align__(16) unsigned char smem[16384];
    float* gbufF = (float*)(smem + 8192);

    const int tid = threadIdx.x;
    const int w = tid >> 6;          // wave 0..3
    const int l = tid & 63;          // lane
    const int quad = l >> 4;
    const int i16 = l & 15;
    const int bid = blockIdx.x;
    const int b0 = bid * 16;
    const int b_loc = 4 * w + quad;  // this thread's sample (phase 1)

    // ---- Hoisted loads: this thread's full x sample (consumed in phase 1).
    // In flight through phases 0a/0b.
    union F8 { float4 v[2]; float f[8]; };
    F8 X[4];                         // [t], 32 VGPRs
    {
        const float* xb = x + (size_t)(b0 + b_loc) * 512 + i16 * 8;
        #pragma unroll
        for (int t = 0; t < 4; ++t) {
            X[t].v[0] = *(const float4*)(xb + t * 128);
            X[t].v[1] = *(const float4*)(xb + t * 128 + 4);
        }
    }

    // ---- Phase 0a: stage y as split bf16 hi/lo in MFMA-A-frag layout.
    // 256 granules (16 rows x 16), one per thread.
    {
        int row = tid >> 4, gk = tid & 15;
        const float* yb = y + (size_t)(b0 + row) * 128 + gk * 8;
        float4 v0 = *(const float4*)(yb);
        float4 v1 = *(const float4*)(yb + 4);
        float f[8] = {v0.x, v0.y, v0.z, v0.w, v1.x, v1.y, v1.z, v1.w};
        uint32_t hi[4], lo[4];
        #pragma unroll
        for (int e = 0; e < 4; ++e) {
            unsigned short h0 = f2bf(f[2 * e]), h1 = f2bf(f[2 * e + 1]);
            hi[e] = (uint32_t)h0 | ((uint32_t)h1 << 16);
            lo[e] = (uint32_t)f2bf(f[2 * e] - bf2f(h0)) |
                    ((uint32_t)f2bf(f[2 * e + 1] - bf2f(h1)) << 16);
        }
        int addr = AADDR(row, gk);         // rows 0..15 -> [0,4K)
        *(uint4*)(smem + addr)        = make_uint4(hi[0], hi[1], hi[2], hi[3]);
        *(uint4*)(smem + 4096 + addr) = make_uint4(lo[0], lo[1], lo[2], lo[3]);
    }
    __syncthreads();

    // ---- Phase 0b: g = Y @ G^T (split precision), column-split waves.
    {
        f32x4 accg[2];                     // [col-block n]
        accg[0] = (f32x4){0.f, 0.f, 0.f, 0.f};
        accg[1] = (f32x4){0.f, 0.f, 0.f, 0.f};
        #pragma unroll
        for (int ks = 0; ks < 4; ++ks) {
            int ksr = (ks + bid) & 3;                    // per-block rotation
            int aaddr = AADDR(i16, ksr * 4 + quad);
            bf16x8 ah = *(const bf16x8*)(smem + aaddr);
            bf16x8 al = *(const bf16x8*)(smem + 4096 + aaddr);
            #pragma unroll
            for (int n = 0; n < 2; ++n) {
                int off = ((2 * w + n) * 16 + i16) * 128 + ksr * 32 + quad * 8;
                bf16x8 bh = *(const bf16x8*)(Gh + off);
                bf16x8 bl = *(const bf16x8*)(Gl + off);
                accg[n] = __builtin_amdgcn_mfma_f32_16x16x32_bf16(ah, bh, accg[n], 0, 0, 0);
                accg[n] = __builtin_amdgcn_mfma_f32_16x16x32_bf16(al, bh, accg[n], 0, 0, 0);
                accg[n] = __builtin_amdgcn_mfma_f32_16x16x32_bf16(ah, bl, accg[n], 0, 0, 0);
            }
        }
        // C-frag: col = i16 (i offset), row = quad*4+r (sample) -> gbuf fp32
        #pragma unroll
        for (int n = 0; n < 2; ++n) {
            int i = (2 * w + n) * 16 + i16;
            #pragma unroll
            for (int r = 0; r < 4; ++r)
                gbufF[(quad * 4 + r) * 128 + i] = accg[n][r];
        }
    }
    __syncthreads();   // g rows assembled from all four waves' col-blocks

    // ---- Phase 1: dots + softmax + U build. One sample per (wave,quad),
    // x already in registers. Lane owns channels [8*i16, +8).
    {
        float4 ga = *(const float4*)(gbufF + b_loc * 128 + i16 * 8);
        float4 gb = *(const float4*)(gbufF + b_loc * 128 + i16 * 8 + 4);
        float p[4];
        #pragma unroll
        for (int t = 0; t < 4; ++t) {
            float4 a = X[t].v[0], b = X[t].v[1];
            p[t] = a.x * ga.x + a.y * ga.y + a.z * ga.z + a.w * ga.w
                 + b.x * gb.x + b.y * gb.y + b.z * gb.z + b.w * gb.w;
        }
        #pragma unroll
        for (int off = 8; off >= 1; off >>= 1) {
            p[0] += __shfl_xor(p[0], off);
            p[1] += __shfl_xor(p[1], off);
            p[2] += __shfl_xor(p[2], off);
            p[3] += __shfl_xor(p[3], off);
        }
        float mx = fmaxf(fmaxf(p[0], p[1]), fmaxf(p[2], p[3]));
        float e0 = __expf(p[0] - mx), e1 = __expf(p[1] - mx);
        float e2 = __expf(p[2] - mx), e3 = __expf(p[3] - mx);
        float inv = 1.f / (e0 + e1 + e2 + e3);
        float w0 = e0 * inv, w1 = e1 * inv, w2 = e2 * inv, w3 = e3 * inv;
        int r0 = 2 * b_loc;
        int a0 = AADDR(r0, i16), a1 = AADDR(r0 + 1, i16);
        uint32_t eL[4], oL[4], eH[4], oH[4];
        #pragma unroll
        for (int e = 0; e < 4; ++e) {
            int c0 = 2 * e, c1 = 2 * e + 1;
            eL[e] = pack2bf(w0 * X[0].f[c0] + w1 * X[1].f[c0], w0 * X[0].f[c1] + w1 * X[1].f[c1]);
            oL[e] = pack2bf(w0 * X[0].f[c0] - w1 * X[1].f[c0], w0 * X[0].f[c1] - w1 * X[1].f[c1]);
            eH[e] = pack2bf(w2 * X[2].f[c0] + w3 * X[3].f[c0], w2 * X[2].f[c1] + w3 * X[3].f[c1]);
            oH[e] = pack2bf(w2 * X[2].f[c0] - w3 * X[3].f[c0], w2 * X[2].f[c1] - w3 * X[3].f[c1]);
        }
        *(uint4*)(smem + a0)        = make_uint4(eL[0], eL[1], eL[2], eL[3]);
        *(uint4*)(smem + a1)        = make_uint4(oL[0], oL[1], oL[2], oL[3]);
        *(uint4*)(smem + 8192 + a0) = make_uint4(eH[0], eH[1], eH[2], eH[3]);
        *(uint4*)(smem + 8192 + a1) = make_uint4(oH[0], oH[1], oH[2], oH[3]);
    }
    __syncthreads();   // phase 2 reads all waves' U rows

    // ---- Phase 2: Z = U(32x256) @ M^T (K=256), single-bf16 M, column-split:
    // wave w owns channels [32w,+32), both row-blocks -> B reuse = 2 MFMAs.
    f32x4 acc[2][2];   // [row-block rb][col-block n]
    #pragma unroll
    for (int rb = 0; rb < 2; ++rb)
        #pragma unroll
        for (int n = 0; n < 2; ++n) acc[rb][n] = (f32x4){0.f, 0.f, 0.f, 0.f};

    #pragma unroll
    for (int ks = 0; ks < 8; ++ks) {
        int ksr = (ks + bid) & 7;                  // per-block rotation
        int half = ksr >> 2, kk = ksr & 3;
        int base = half << 13;                     // 0 (U-low) or 8192 (U-high)
        int gi = kk * 4 + quad;
        bf16x8 a0v = *(const bf16x8*)(smem + base + AADDR(i16, gi));
        bf16x8 a1v = *(const bf16x8*)(smem + base + AADDR(16 + i16, gi));
        #pragma unroll
        for (int n = 0; n < 2; ++n) {
            bf16x8 bh = *(const bf16x8*)(Mh + ((2 * w + n) * 16 + i16) * 256 + half * 128 + kk * 32 + quad * 8);
            acc[0][n] = __builtin_amdgcn_mfma_f32_16x16x32_bf16(a0v, bh, acc[0][n], 0, 0, 0);
            acc[1][n] = __builtin_amdgcn_mfma_f32_16x16x32_bf16(a1v, bh, acc[1][n], 0, 0, 0);
        }
    }

    // ---- Epilogue: scale/bias/LeakyReLU, j-contiguous float4 stores.
    // Block covers j in [ (bid&31)*32, +32 ) of group bid>>5.
    {
        float* outp = out + (size_t)(bid >> 5) * 131072 + (bid & 31) * 32;
        #pragma unroll
        for (int n = 0; n < 2; ++n) {
            int o = (2 * w + n) * 16 + i16;
            float sc = scale2[o], bi = bias2[o];
            #pragma unroll
            for (int rb = 0; rb < 2; ++rb) {
                int jb = 16 * rb + quad * 4;
                f32x4 a = acc[rb][n];
                float4 r;
                r.x = lrelu(a[0] * sc + bi);
                r.y = lrelu(a[1] * sc + bi);
                r.z = lrelu(a[2] * sc + bi);
                r.w = lrelu(a[3] * sc + bi);
                *(float4*)(outp + (size_t)o * 1024 + jb) = r;
            }
        }
    }
}

extern "C" void kernel_launch(void* const* d_in, const int* in_sizes, int n_in,
                              void* d_out, int out_size, void* d_ws, size_t ws_size,
                              hipStream_t stream)
{
    (void)in_sizes; (void)n_in; (void)out_size; (void)ws_size;
    const float* x        = (const float*)d_in[0];
    const float* y        = (const float*)d_in[1];
    const float* Wq       = (const float*)d_in[2];
    const float* Wk       = (const float*)d_in[3];
    const float* Wv       = (const float*)d_in[4];
    const float* conv_w   = (const float*)d_in[5];
    const float* conv_b   = (const float*)d_in[6];
    const float* bn_gamma = (const float*)d_in[7];
    const float* bn_beta  = (const float*)d_in[8];
    const float* bn_mean  = (const float*)d_in[9];
    const float* bn_var   = (const float*)d_in[10];

    unsigned char* ws = (unsigned char*)d_ws;
    unsigned short* Gh = (unsigned short*)(ws);                // 32 KB
    unsigned short* Gl = (unsigned short*)(ws + 32768);        // 32 KB
    unsigned short* Mh = (unsigned short*)(ws + 65536);        // 64 KB
    float* scale2      = (float*)(ws + 131072);                // 512 B
    float* bias2       = (float*)(ws + 131584);                // 512 B

    hipLaunchKernelGGL(precompute_kernel, dim3(193), dim3(256), 0, stream,
                       Wq, Wk, Wv, conv_w, conv_b, bn_gamma, bn_beta, bn_mean,
                       bn_var, Gh, Gl, Mh, scale2, bias2);
    hipLaunchKernelGGL(fused_kernel, dim3(2048), dim3(256), 0, stream,
                       x, y, Gh, Gl, Mh, scale2, bias2, (float*)d_out);
}

// Round 2
// 158.242 us; speedup vs baseline: 1.0788x; 1.0788x over previous
//
#include <hip/hip_runtime.h>
#include <stdint.h>

// Problem constants
//  B = 32768 samples, T_X = 4, K = 128, 64 groups x 512, out = (64,128,1,1024) fp32
typedef __attribute__((ext_vector_type(8))) short bf16x8;  // 8 bf16 in 4 VGPRs
typedef __attribute__((ext_vector_type(4))) float f32x4;

__device__ __forceinline__ unsigned short f2bf(float x) {
    union { float f; uint32_t u; } v; v.f = x;
    uint32_t r = v.u + 0x7FFFu + ((v.u >> 16) & 1u);   // RNE
    return (unsigned short)(r >> 16);
}
__device__ __forceinline__ uint32_t pack2bf(float a, float b) {
    return (uint32_t)f2bf(a) | ((uint32_t)f2bf(b) << 16);
}
__device__ __forceinline__ float bf2f(uint32_t lo) {
    union { uint32_t u; float f; } v; v.u = lo << 16; return v.f;
}
__device__ __forceinline__ float lrelu(float v) { return v > 0.f ? v : 0.01f * v; }

// ---------------------------------------------------------------------------
// K0: precompute (LDS-tiled small GEMMs, coalesced staging) — unchanged
//   G (split hi/lo bf16): G[i][j] = (1/sqrt(128)) * sum_o Wk[o,i]*Wq[o,j]
//   M (single bf16 RNE):  M[o][c] = inv_sqrt2 * sum_k conv_w[o,(c>>7)*128+k]*Wv[k,c&127]
//   blocks 0..63: G 16x16 tiles; 64..191: M 16x16 tiles; 192: BN constants
// ---------------------------------------------------------------------------
__global__ __launch_bounds__(256) void precompute_kernel(
    const float* __restrict__ Wq, const float* __restrict__ Wk,
    const float* __restrict__ Wv, const float* __restrict__ conv_w,
    const float* __restrict__ conv_b, const float* __restrict__ bn_gamma,
    const float* __restrict__ bn_beta, const float* __restrict__ bn_mean,
    const float* __restrict__ bn_var,
    unsigned short* __restrict__ Gh, unsigned short* __restrict__ Gl,
    unsigned short* __restrict__ Mh,
    float* __restrict__ scale2, float* __restrict__ bias2)
{
    __shared__ float lds0[2176];   // 128x16 pad17 (8704 B) or 16x128 pad132
    __shared__ float lds1[2176];   // 128x16 pad17
    const int tid = threadIdx.x;
    const int bid = blockIdx.x;

    if (bid == 192) {                              // constants
        if (tid < 128) {
            float sc = bn_gamma[tid] * rsqrtf(bn_var[tid] + 1e-5f);
            scale2[tid] = sc;
            bias2[tid]  = (conv_b[tid] - bn_mean[tid]) * sc + bn_beta[tid];
        }
        return;
    }

    if (bid < 64) {                                // ---- G tile (i0, j0)
        int i0 = (bid >> 3) << 4, j0 = (bid & 7) << 4;
        #pragma unroll
        for (int t = 0; t < 8; ++t) {              // stage col-tiles, 64B lines
            int e = tid + t * 256;
            int o = e >> 4, c = e & 15;
            lds0[o * 17 + c] = Wk[o * 128 + i0 + c];
            lds1[o * 17 + c] = Wq[o * 128 + j0 + c];
        }
        __syncthreads();
        int ti = tid >> 4, tj = tid & 15;
        float sum = 0.f;
        #pragma unroll 8
        for (int o = 0; o < 128; ++o) sum += lds0[o * 17 + ti] * lds1[o * 17 + tj];
        float val = sum * 0.08838834764831845f;    // 1/sqrt(128)
        unsigned short h = f2bf(val);
        int idx = (i0 + ti) * 128 + j0 + tj;
        Gh[idx] = h;
        Gl[idx] = f2bf(val - bf2f(h));
    } else {                                       // ---- M tile (o0, c0)
        int rel = bid - 64;
        int o0 = (rel >> 4) << 4, c0 = (rel & 15) << 4;
        int cw0 = (c0 >> 7) << 7, cc0 = c0 & 127;
        #pragma unroll
        for (int t = 0; t < 8; ++t) {
            int e = tid + t * 256;
            int to = e >> 7, k = e & 127;          // conv_w rows: contiguous
            lds0[to * 132 + k] = conv_w[(o0 + to) * 256 + cw0 + k];
            int kk = e >> 4, c = e & 15;           // Wv col-tile
            lds1[kk * 17 + c] = Wv[kk * 128 + cc0 + c];
        }
        __syncthreads();
        int to = tid >> 4, tc = tid & 15;
        float sum = 0.f;
        #pragma unroll 8
        for (int k = 0; k < 128; ++k) sum += lds0[to * 132 + k] * lds1[k * 17 + tc];
        Mh[(o0 + to) * 256 + c0 + tc] = f2bf(sum * 0.7071067811865476f);
    }
}

// ---------------------------------------------------------------------------
// K1: fused attention + IDWT + conv + BN + LeakyReLU.
// r8 changes vs r7: keep 16-sample / 2048-block geometry but pin codegen at
// the 4-waves/EU register tier: amdgpu_waves_per_eu(4,4) -> 128-reg budget,
// no occupancy-boost shrink to 64/32 regs. r7's launch_bounds(256,8) gave a
// 64-reg TOTAL budget (unified VGPR/AGPR file) -> X spilled to scratch
// (VGPR=32, WRITE_SIZE 33->55 MB). r6's heuristic 64-reg target silently sank
// the X loads into phase 1 (cold-HBM stall behind two barriers). With 128
// regs X stays resident from entry: x-stream latency hides under phases
// 0a/0b. Explicit first-ks G/M fragment prefetches re-added.
// LDS overlays (16-row geometry):
//   [0,8K)   phase0: y bf16 hi [0,4K) + lo [4K,8K)  ->  phase1+: U-low bf16 (32 rows)
//   [8K,16K) phase0b out: gbuf fp32 (16 x 128)      ->  phase1+: U-high bf16
// U-high row pair 2*b_loc,2*b_loc+1 lands exactly on the gbuf row b_loc the
// same thread just consumed (same-wave read-before-write => no hazard).
// ---------------------------------------------------------------------------
#define AADDR(row, gi)   (((row) << 8) + ((((gi) ^ ((row) & 7))) << 4))

__global__ __launch_bounds__(256)
__attribute__((amdgpu_waves_per_eu(4, 4)))
void fused_kernel(
    const float* __restrict__ x, const float* __restrict__ y,
    const unsigned short* __restrict__ Gh, const unsigned short* __restrict__ Gl,
    const unsigned short* __restrict__ Mh,
    const float* __restrict__ scale2, const float* __restrict__ bias2,
    float* __restrict__ out)
{
    __shared__ __align__(16) unsigned char smem[16384];
    float* gbufF = (float*)(smem + 8192);

    const int tid = threadIdx.x;
    const int w = tid >> 6;          // wave 0..3
    const int l = tid & 63;          // lane
    const int quad = l >> 4;
    const int i16 = l & 15;
    const int bid = blockIdx.x;
    const int b0 = bid * 16;
    const int b_loc = 4 * w + quad;  // this thread's sample (phase 1)

    // ---- Hoisted loads: this thread's full x sample (consumed in phase 1)
    // and the first-ks G B-frags (consumed at phase 0b ks=0). With the
    // 128-reg budget these stay in flight through phases 0a/0b.
    union F8 { float4 v[2]; float f[8]; };
    F8 X[4];                         // [t], 32 VGPRs
    {
        const float* xb = x + (size_t)(b0 + b_loc) * 512 + i16 * 8;
        #pragma unroll
        for (int t = 0; t < 4; ++t) {
            X[t].v[0] = *(const float4*)(xb + t * 128);
            X[t].v[1] = *(const float4*)(xb + t * 128 + 4);
        }
    }
    const int ks0 = bid & 3;
    bf16x8 pgh[2], pgl[2];
    #pragma unroll
    for (int n = 0; n < 2; ++n) {
        int off = ((2 * w + n) * 16 + i16) * 128 + ks0 * 32 + quad * 8;
        pgh[n] = *(const bf16x8*)(Gh + off);
        pgl[n] = *(const bf16x8*)(Gl + off);
    }

    // ---- Phase 0a: stage y as split bf16 hi/lo in MFMA-A-frag layout.
    // 256 granules (16 rows x 16), one per thread.
    {
        int row = tid >> 4, gk = tid & 15;
        const float* yb = y + (size_t)(b0 + row) * 128 + gk * 8;
        float4 v0 = *(const float4*)(yb);
        float4 v1 = *(const float4*)(yb + 4);
        float f[8] = {v0.x, v0.y, v0.z, v0.w, v1.x, v1.y, v1.z, v1.w};
        uint32_t hi[4], lo[4];
        #pragma unroll
        for (int e = 0; e < 4; ++e) {
            unsigned short h0 = f2bf(f[2 * e]), h1 = f2bf(f[2 * e + 1]);
            hi[e] = (uint32_t)h0 | ((uint32_t)h1 << 16);
            lo[e] = (uint32_t)f2bf(f[2 * e] - bf2f(h0)) |
                    ((uint32_t)f2bf(f[2 * e + 1] - bf2f(h1)) << 16);
        }
        int addr = AADDR(row, gk);         // rows 0..15 -> [0,4K)
        *(uint4*)(smem + addr)        = make_uint4(hi[0], hi[1], hi[2], hi[3]);
        *(uint4*)(smem + 4096 + addr) = make_uint4(lo[0], lo[1], lo[2], lo[3]);
    }
    __syncthreads();

    // ---- Phase 0b: g = Y @ G^T (split precision), column-split waves.
    {
        f32x4 accg[2];                     // [col-block n]
        accg[0] = (f32x4){0.f, 0.f, 0.f, 0.f};
        accg[1] = (f32x4){0.f, 0.f, 0.f, 0.f};
        #pragma unroll
        for (int ks = 0; ks < 4; ++ks) {
            int ksr = (ks + bid) & 3;                    // per-block rotation
            int aaddr = AADDR(i16, ksr * 4 + quad);
            bf16x8 ah = *(const bf16x8*)(smem + aaddr);
            bf16x8 al = *(const bf16x8*)(smem + 4096 + aaddr);
            #pragma unroll
            for (int n = 0; n < 2; ++n) {
                bf16x8 bh, bl;
                if (ks == 0) { bh = pgh[n]; bl = pgl[n]; }
                else {
                    int off = ((2 * w + n) * 16 + i16) * 128 + ksr * 32 + quad * 8;
                    bh = *(const bf16x8*)(Gh + off);
                    bl = *(const bf16x8*)(Gl + off);
                }
                accg[n] = __builtin_amdgcn_mfma_f32_16x16x32_bf16(ah, bh, accg[n], 0, 0, 0);
                accg[n] = __builtin_amdgcn_mfma_f32_16x16x32_bf16(al, bh, accg[n], 0, 0, 0);
                accg[n] = __builtin_amdgcn_mfma_f32_16x16x32_bf16(ah, bl, accg[n], 0, 0, 0);
            }
        }
        // C-frag: col = i16 (i offset), row = quad*4+r (sample) -> gbuf fp32
        #pragma unroll
        for (int n = 0; n < 2; ++n) {
            int i = (2 * w + n) * 16 + i16;
            #pragma unroll
            for (int r = 0; r < 4; ++r)
                gbufF[(quad * 4 + r) * 128 + i] = accg[n][r];
        }
    }
    __syncthreads();   // g rows assembled from all four waves' col-blocks

    // ---- Phase 1: dots + softmax + U build. One sample per (wave,quad),
    // x already in registers. Lane owns channels [8*i16, +8).
    {
        float4 ga = *(const float4*)(gbufF + b_loc * 128 + i16 * 8);
        float4 gb = *(const float4*)(gbufF + b_loc * 128 + i16 * 8 + 4);
        float p[4];
        #pragma unroll
        for (int t = 0; t < 4; ++t) {
            float4 a = X[t].v[0], b = X[t].v[1];
            p[t] = a.x * ga.x + a.y * ga.y + a.z * ga.z + a.w * ga.w
                 + b.x * gb.x + b.y * gb.y + b.z * gb.z + b.w * gb.w;
        }
        #pragma unroll
        for (int off = 8; off >= 1; off >>= 1) {
            p[0] += __shfl_xor(p[0], off);
            p[1] += __shfl_xor(p[1], off);
            p[2] += __shfl_xor(p[2], off);
            p[3] += __shfl_xor(p[3], off);
        }
        float mx = fmaxf(fmaxf(p[0], p[1]), fmaxf(p[2], p[3]));
        float e0 = __expf(p[0] - mx), e1 = __expf(p[1] - mx);
        float e2 = __expf(p[2] - mx), e3 = __expf(p[3] - mx);
        float inv = 1.f / (e0 + e1 + e2 + e3);
        float w0 = e0 * inv, w1 = e1 * inv, w2 = e2 * inv, w3 = e3 * inv;
        int r0 = 2 * b_loc;
        int a0 = AADDR(r0, i16), a1 = AADDR(r0 + 1, i16);
        uint32_t eL[4], oL[4], eH[4], oH[4];
        #pragma unroll
        for (int e = 0; e < 4; ++e) {
            int c0 = 2 * e, c1 = 2 * e + 1;
            eL[e] = pack2bf(w0 * X[0].f[c0] + w1 * X[1].f[c0], w0 * X[0].f[c1] + w1 * X[1].f[c1]);
            oL[e] = pack2bf(w0 * X[0].f[c0] - w1 * X[1].f[c0], w0 * X[0].f[c1] - w1 * X[1].f[c1]);
            eH[e] = pack2bf(w2 * X[2].f[c0] + w3 * X[3].f[c0], w2 * X[2].f[c1] + w3 * X[3].f[c1]);
            oH[e] = pack2bf(w2 * X[2].f[c0] - w3 * X[3].f[c0], w2 * X[2].f[c1] - w3 * X[3].f[c1]);
        }
        *(uint4*)(smem + a0)        = make_uint4(eL[0], eL[1], eL[2], eL[3]);
        *(uint4*)(smem + a1)        = make_uint4(oL[0], oL[1], oL[2], oL[3]);
        *(uint4*)(smem + 8192 + a0) = make_uint4(eH[0], eH[1], eH[2], eH[3]);
        *(uint4*)(smem + 8192 + a1) = make_uint4(oH[0], oH[1], oH[2], oH[3]);
    }

    // Prefetch phase-2 first-ks B-frags before the barrier
    const int ks0b = bid & 7;
    bf16x8 pmh[2];
    {
        int half = ks0b >> 2, kk = ks0b & 3;
        #pragma unroll
        for (int n = 0; n < 2; ++n)
            pmh[n] = *(const bf16x8*)(Mh + ((2 * w + n) * 16 + i16) * 256 + half * 128 + kk * 32 + quad * 8);
    }
    __syncthreads();   // phase 2 reads all waves' U rows

    // ---- Phase 2: Z = U(32x256) @ M^T (K=256), single-bf16 M, column-split:
    // wave w owns channels [32w,+32), both row-blocks -> B reuse = 2 MFMAs.
    f32x4 acc[2][2];   // [row-block rb][col-block n]
    #pragma unroll
    for (int rb = 0; rb < 2; ++rb)
        #pragma unroll
        for (int n = 0; n < 2; ++n) acc[rb][n] = (f32x4){0.f, 0.f, 0.f, 0.f};

    #pragma unroll
    for (int ks = 0; ks < 8; ++ks) {
        int ksr = (ks + bid) & 7;                  // per-block rotation
        int half = ksr >> 2, kk = ksr & 3;
        int base = half << 13;                     // 0 (U-low) or 8192 (U-high)
        int gi = kk * 4 + quad;
        bf16x8 a0v = *(const bf16x8*)(smem + base + AADDR(i16, gi));
        bf16x8 a1v = *(const bf16x8*)(smem + base + AADDR(16 + i16, gi));
        #pragma unroll
        for (int n = 0; n < 2; ++n) {
            bf16x8 bh;
            if (ks == 0) bh = pmh[n];
            else bh = *(const bf16x8*)(Mh + ((2 * w + n) * 16 + i16) * 256 + half * 128 + kk * 32 + quad * 8);
            acc[0][n] = __builtin_amdgcn_mfma_f32_16x16x32_bf16(a0v, bh, acc[0][n], 0, 0, 0);
            acc[1][n] = __builtin_amdgcn_mfma_f32_16x16x32_bf16(a1v, bh, acc[1][n], 0, 0, 0);
        }
    }

    // ---- Epilogue: scale/bias/LeakyReLU, j-contiguous float4 stores.
    // Block covers j in [ (bid&31)*32, +32 ) of group bid>>5.
    {
        float* outp = out + (size_t)(bid >> 5) * 131072 + (bid & 31) * 32;
        #pragma unroll
        for (int n = 0; n < 2; ++n) {
            int o = (2 * w + n) * 16 + i16;
            float sc = scale2[o], bi = bias2[o];
            #pragma unroll
            for (int rb = 0; rb < 2; ++rb) {
                int jb = 16 * rb + quad * 4;
                f32x4 a = acc[rb][n];
                float4 r;
                r.x = lrelu(a[0] * sc + bi);
                r.y = lrelu(a[1] * sc + bi);
                r.z = lrelu(a[2] * sc + bi);
                r.w = lrelu(a[3] * sc + bi);
                *(float4*)(outp + (size_t)o * 1024 + jb) = r;
            }
        }
    }
}

extern "C" void kernel_launch(void* const* d_in, const int* in_sizes, int n_in,
                              void* d_out, int out_size, void* d_ws, size_t ws_size,
                              hipStream_t stream)
{
    (void)in_sizes; (void)n_in; (void)out_size; (void)ws_size;
    const float* x        = (const float*)d_in[0];
    const float* y        = (const float*)d_in[1];
    const float* Wq       = (const float*)d_in[2];
    const float* Wk       = (const float*)d_in[3];
    const float* Wv       = (const float*)d_in[4];
    const float* conv_w   = (const float*)d_in[5];
    const float* conv_b   = (const float*)d_in[6];
    const float* bn_gamma = (const float*)d_in[7];
    const float* bn_beta  = (const float*)d_in[8];
    const float* bn_mean  = (const float*)d_in[9];
    const float* bn_var   = (const float*)d_in[10];

    unsigned char* ws = (unsigned char*)d_ws;
    unsigned short* Gh = (unsigned short*)(ws);                // 32 KB
    unsigned short* Gl = (unsigned short*)(ws + 32768);        // 32 KB
    unsigned short* Mh = (unsigned short*)(ws + 65536);        // 64 KB
    float* scale2      = (float*)(ws + 131072);                // 512 B
    float* bias2       = (float*)(ws + 131584);                // 512 B

    hipLaunchKernelGGL(precompute_kernel, dim3(193), dim3(256), 0, stream,
                       Wq, Wk, Wv, conv_w, conv_b, bn_gamma, bn_beta, bn_mean,
                       bn_var, Gh, Gl, Mh, scale2, bias2);
    hipLaunchKernelGGL(fused_kernel, dim3(2048), dim3(256), 0, stream,
                       x, y, Gh, Gl, Mh, scale2, bias2, (float*)d_out);
}

// Round 3
// 156.274 us; speedup vs baseline: 1.0924x; 1.0126x over previous
//
#include <hip/hip_runtime.h>
#include <stdint.h>

// Problem constants
//  B = 32768 samples, T_X = 4, K = 128, 64 groups x 512, out = (64,128,1,1024) fp32
typedef __attribute__((ext_vector_type(8))) short bf16x8;  // 8 bf16 in 4 VGPRs
typedef __attribute__((ext_vector_type(4))) float f32x4;

__device__ __forceinline__ unsigned short f2bf(float x) {
    union { float f; uint32_t u; } v; v.f = x;
    uint32_t r = v.u + 0x7FFFu + ((v.u >> 16) & 1u);   // RNE
    return (unsigned short)(r >> 16);
}
__device__ __forceinline__ uint32_t pack2bf(float a, float b) {
    return (uint32_t)f2bf(a) | ((uint32_t)f2bf(b) << 16);
}
__device__ __forceinline__ float bf2f(uint32_t lo) {
    union { uint32_t u; float f; } v; v.u = lo << 16; return v.f;
}
__device__ __forceinline__ float lrelu(float v) { return v > 0.f ? v : 0.01f * v; }

// ---------------------------------------------------------------------------
// K0: precompute (LDS-tiled small GEMMs, coalesced staging) — unchanged
//   G (split hi/lo bf16): G[i][j] = (1/sqrt(128)) * sum_o Wk[o,i]*Wq[o,j]
//   M (single bf16 RNE):  M[o][c] = inv_sqrt2 * sum_k conv_w[o,(c>>7)*128+k]*Wv[k,c&127]
//   blocks 0..63: G 16x16 tiles; 64..191: M 16x16 tiles; 192: BN constants
// ---------------------------------------------------------------------------
__global__ __launch_bounds__(256) void precompute_kernel(
    const float* __restrict__ Wq, const float* __restrict__ Wk,
    const float* __restrict__ Wv, const float* __restrict__ conv_w,
    const float* __restrict__ conv_b, const float* __restrict__ bn_gamma,
    const float* __restrict__ bn_beta, const float* __restrict__ bn_mean,
    const float* __restrict__ bn_var,
    unsigned short* __restrict__ Gh, unsigned short* __restrict__ Gl,
    unsigned short* __restrict__ Mh,
    float* __restrict__ scale2, float* __restrict__ bias2)
{
    __shared__ float lds0[2176];   // 128x16 pad17 (8704 B) or 16x128 pad132
    __shared__ float lds1[2176];   // 128x16 pad17
    const int tid = threadIdx.x;
    const int bid = blockIdx.x;

    if (bid == 192) {                              // constants
        if (tid < 128) {
            float sc = bn_gamma[tid] * rsqrtf(bn_var[tid] + 1e-5f);
            scale2[tid] = sc;
            bias2[tid]  = (conv_b[tid] - bn_mean[tid]) * sc + bn_beta[tid];
        }
        return;
    }

    if (bid < 64) {                                // ---- G tile (i0, j0)
        int i0 = (bid >> 3) << 4, j0 = (bid & 7) << 4;
        #pragma unroll
        for (int t = 0; t < 8; ++t) {              // stage col-tiles, 64B lines
            int e = tid + t * 256;
            int o = e >> 4, c = e & 15;
            lds0[o * 17 + c] = Wk[o * 128 + i0 + c];
            lds1[o * 17 + c] = Wq[o * 128 + j0 + c];
        }
        __syncthreads();
        int ti = tid >> 4, tj = tid & 15;
        float sum = 0.f;
        #pragma unroll 8
        for (int o = 0; o < 128; ++o) sum += lds0[o * 17 + ti] * lds1[o * 17 + tj];
        float val = sum * 0.08838834764831845f;    // 1/sqrt(128)
        unsigned short h = f2bf(val);
        int idx = (i0 + ti) * 128 + j0 + tj;
        Gh[idx] = h;
        Gl[idx] = f2bf(val - bf2f(h));
    } else {                                       // ---- M tile (o0, c0)
        int rel = bid - 64;
        int o0 = (rel >> 4) << 4, c0 = (rel & 15) << 4;
        int cw0 = (c0 >> 7) << 7, cc0 = c0 & 127;
        #pragma unroll
        for (int t = 0; t < 8; ++t) {
            int e = tid + t * 256;
            int to = e >> 7, k = e & 127;          // conv_w rows: contiguous
            lds0[to * 132 + k] = conv_w[(o0 + to) * 256 + cw0 + k];
            int kk = e >> 4, c = e & 15;           // Wv col-tile
            lds1[kk * 17 + c] = Wv[kk * 128 + cc0 + c];
        }
        __syncthreads();
        int to = tid >> 4, tc = tid & 15;
        float sum = 0.f;
        #pragma unroll 8
        for (int k = 0; k < 128; ++k) sum += lds0[to * 132 + k] * lds1[k * 17 + tc];
        Mh[(o0 + to) * 256 + c0 + tc] = f2bf(sum * 0.7071067811865476f);
    }
}

#define AADDR(row, gi)   (((row) << 8) + ((((gi) ^ ((row) & 7))) << 4))

// ---------------------------------------------------------------------------
// KA (r9, new): g = Y @ G^T for all samples, split-precision bf16 MFMA.
// 1024 blocks x 32 samples. Pulled out of the fused kernel so the big x-read
// kernel has NO pre-x phases (in-order vmcnt retirement made the fused
// version stall on its whole entry queue before phase 0a could start).
// y loads issue FIRST; the only other globals are L2-resident G fragments.
// ---------------------------------------------------------------------------
__global__ __launch_bounds__(256) void g_kernel(
    const float* __restrict__ y,
    const unsigned short* __restrict__ Gh, const unsigned short* __restrict__ Gl,
    float* __restrict__ g)
{
    __shared__ __align__(16) unsigned char smem[16384];  // y hi [0,8K) + lo [8K,16K)
    const int tid = threadIdx.x;
    const int w = tid >> 6;
    const int l = tid & 63;
    const int quad = l >> 4;
    const int i16 = l & 15;
    const int bid = blockIdx.x;
    const int b0 = bid * 32;

    // ---- y loads first (needed first); then G ks0 prefetch (needed second).
    float4 yv[2][2];
    int rowA[2], gkA[2];
    #pragma unroll
    for (int it = 0; it < 2; ++it) {
        int j = tid + it * 256;                // 512 granules: 32 rows x 16
        rowA[it] = j >> 4; gkA[it] = j & 15;
        const float* yb = y + (size_t)(b0 + rowA[it]) * 128 + gkA[it] * 8;
        yv[it][0] = *(const float4*)(yb);
        yv[it][1] = *(const float4*)(yb + 4);
    }
    const int ks0 = bid & 3;
    bf16x8 pgh[2], pgl[2];
    #pragma unroll
    for (int n = 0; n < 2; ++n) {
        int off = ((2 * w + n) * 16 + i16) * 128 + ks0 * 32 + quad * 8;
        pgh[n] = *(const bf16x8*)(Gh + off);
        pgl[n] = *(const bf16x8*)(Gl + off);
    }

    // ---- pack y split bf16 hi/lo into MFMA-A-frag layout
    #pragma unroll
    for (int it = 0; it < 2; ++it) {
        float f[8] = {yv[it][0].x, yv[it][0].y, yv[it][0].z, yv[it][0].w,
                      yv[it][1].x, yv[it][1].y, yv[it][1].z, yv[it][1].w};
        uint32_t hi[4], lo[4];
        #pragma unroll
        for (int e = 0; e < 4; ++e) {
            unsigned short h0 = f2bf(f[2 * e]), h1 = f2bf(f[2 * e + 1]);
            hi[e] = (uint32_t)h0 | ((uint32_t)h1 << 16);
            lo[e] = (uint32_t)f2bf(f[2 * e] - bf2f(h0)) |
                    ((uint32_t)f2bf(f[2 * e + 1] - bf2f(h1)) << 16);
        }
        int addr = AADDR(rowA[it], gkA[it]);
        *(uint4*)(smem + addr)        = make_uint4(hi[0], hi[1], hi[2], hi[3]);
        *(uint4*)(smem + 8192 + addr) = make_uint4(lo[0], lo[1], lo[2], lo[3]);
    }
    __syncthreads();

    // ---- g = Y @ G^T (split precision), column-split waves
    f32x4 accg[2][2];    // [sample-tile rt][col-block n]
    #pragma unroll
    for (int rt = 0; rt < 2; ++rt)
        #pragma unroll
        for (int n = 0; n < 2; ++n) accg[rt][n] = (f32x4){0.f, 0.f, 0.f, 0.f};
    #pragma unroll
    for (int ks = 0; ks < 4; ++ks) {
        int ksr = (ks + bid) & 3;                    // per-block rotation
        bf16x8 ah[2], al[2];
        #pragma unroll
        for (int rt = 0; rt < 2; ++rt) {
            int row = 16 * rt + i16;
            int addr = AADDR(row, ksr * 4 + quad);
            ah[rt] = *(const bf16x8*)(smem + addr);
            al[rt] = *(const bf16x8*)(smem + 8192 + addr);
        }
        #pragma unroll
        for (int n = 0; n < 2; ++n) {
            bf16x8 bh, bl;
            if (ks == 0) { bh = pgh[n]; bl = pgl[n]; }
            else {
                int off = ((2 * w + n) * 16 + i16) * 128 + ksr * 32 + quad * 8;
                bh = *(const bf16x8*)(Gh + off);
                bl = *(const bf16x8*)(Gl + off);
            }
            #pragma unroll
            for (int rt = 0; rt < 2; ++rt) {
                accg[rt][n] = __builtin_amdgcn_mfma_f32_16x16x32_bf16(ah[rt], bh, accg[rt][n], 0, 0, 0);
                accg[rt][n] = __builtin_amdgcn_mfma_f32_16x16x32_bf16(al[rt], bh, accg[rt][n], 0, 0, 0);
                accg[rt][n] = __builtin_amdgcn_mfma_f32_16x16x32_bf16(ah[rt], bl, accg[rt][n], 0, 0, 0);
            }
        }
    }
    // C-frag: col = i16 (i offset), row = quad*4+r (sample) -> g fp32 (global)
    #pragma unroll
    for (int n = 0; n < 2; ++n) {
        int i = (2 * w + n) * 16 + i16;
        #pragma unroll
        for (int rt = 0; rt < 2; ++rt)
            #pragma unroll
            for (int r = 0; r < 4; ++r)
                g[(size_t)(b0 + 16 * rt + quad * 4 + r) * 128 + i] = accg[rt][n][r];
    }
}

// ---------------------------------------------------------------------------
// KB (r9, new): x-stream kernel. 1024 blocks x 32 samples, 32 KB LDS (U only).
// NO pre-x phases: entry queue is [g(4), X(16)] per thread -> the whole chip
// issues the 67 MB x stream immediately with ~320 KB/CU in flight, instead of
// serializing behind a y-pack/MFMA phase (r6's in-order-vmcnt stall).
// Phase 1: dots + softmax + U build (g from registers). Phase 2: Z = U @ M^T.
// LDS: U-low bf16 [0,16K) (64 rows x 256B, granule-swizzled), U-high [16K,32K).
// ---------------------------------------------------------------------------
__global__ __launch_bounds__(256)
__attribute__((amdgpu_waves_per_eu(4, 4)))
void fused2_kernel(
    const float* __restrict__ x, const float* __restrict__ g,
    const unsigned short* __restrict__ Mh,
    const float* __restrict__ scale2, const float* __restrict__ bias2,
    float* __restrict__ out)
{
    __shared__ __align__(16) unsigned char smem[32768];
    const int tid = threadIdx.x;
    const int w = tid >> 6;
    const int l = tid & 63;
    const int quad = l >> 4;
    const int i16 = l & 15;
    const int bid = blockIdx.x;
    const int b0 = bid * 32;

    union F8 { float4 v[2]; float f[8]; };
    // ---- entry loads: g first (used first), then all x
    F8 Gv[2];
    #pragma unroll
    for (int pass = 0; pass < 2; ++pass) {
        int b_loc = 8 * w + pass * 4 + quad;
        const float* gp = g + (size_t)(b0 + b_loc) * 128 + i16 * 8;
        Gv[pass].v[0] = *(const float4*)(gp);
        Gv[pass].v[1] = *(const float4*)(gp + 4);
    }
    F8 X[2][4];
    #pragma unroll
    for (int pass = 0; pass < 2; ++pass) {
        int b_loc = 8 * w + pass * 4 + quad;
        const float* xb = x + (size_t)(b0 + b_loc) * 512 + i16 * 8;
        #pragma unroll
        for (int t = 0; t < 4; ++t) {
            X[pass][t].v[0] = *(const float4*)(xb + t * 128);
            X[pass][t].v[1] = *(const float4*)(xb + t * 128 + 4);
        }
    }

    // ---- Phase 1: dots + softmax + U build. One sample per (wave,pass,quad).
    #pragma unroll
    for (int pass = 0; pass < 2; ++pass) {
        int b_loc = 8 * w + pass * 4 + quad;
        float4 ga = Gv[pass].v[0], gb = Gv[pass].v[1];
        float p[4];
        #pragma unroll
        for (int t = 0; t < 4; ++t) {
            float4 a = X[pass][t].v[0], b = X[pass][t].v[1];
            p[t] = a.x * ga.x + a.y * ga.y + a.z * ga.z + a.w * ga.w
                 + b.x * gb.x + b.y * gb.y + b.z * gb.z + b.w * gb.w;
        }
        #pragma unroll
        for (int off = 8; off >= 1; off >>= 1) {
            p[0] += __shfl_xor(p[0], off);
            p[1] += __shfl_xor(p[1], off);
            p[2] += __shfl_xor(p[2], off);
            p[3] += __shfl_xor(p[3], off);
        }
        float mx = fmaxf(fmaxf(p[0], p[1]), fmaxf(p[2], p[3]));
        float e0 = __expf(p[0] - mx), e1 = __expf(p[1] - mx);
        float e2 = __expf(p[2] - mx), e3 = __expf(p[3] - mx);
        float inv = 1.f / (e0 + e1 + e2 + e3);
        float w0 = e0 * inv, w1 = e1 * inv, w2 = e2 * inv, w3 = e3 * inv;
        int r0 = 2 * b_loc, r1 = r0 + 1;
        int a0 = AADDR(r0, i16), a1 = AADDR(r1, i16);
        uint32_t eL[4], oL[4], eH[4], oH[4];
        #pragma unroll
        for (int e = 0; e < 4; ++e) {
            int c0 = 2 * e, c1 = 2 * e + 1;
            eL[e] = pack2bf(w0 * X[pass][0].f[c0] + w1 * X[pass][1].f[c0], w0 * X[pass][0].f[c1] + w1 * X[pass][1].f[c1]);
            oL[e] = pack2bf(w0 * X[pass][0].f[c0] - w1 * X[pass][1].f[c0], w0 * X[pass][0].f[c1] - w1 * X[pass][1].f[c1]);
            eH[e] = pack2bf(w2 * X[pass][2].f[c0] + w3 * X[pass][3].f[c0], w2 * X[pass][2].f[c1] + w3 * X[pass][3].f[c1]);
            oH[e] = pack2bf(w2 * X[pass][2].f[c0] - w3 * X[pass][3].f[c0], w2 * X[pass][2].f[c1] - w3 * X[pass][3].f[c1]);
        }
        *(uint4*)(smem + a0)         = make_uint4(eL[0], eL[1], eL[2], eL[3]);
        *(uint4*)(smem + a1)         = make_uint4(oL[0], oL[1], oL[2], oL[3]);
        *(uint4*)(smem + 16384 + a0) = make_uint4(eH[0], eH[1], eH[2], eH[3]);
        *(uint4*)(smem + 16384 + a1) = make_uint4(oH[0], oH[1], oH[2], oH[3]);
    }

    // Prefetch phase-2 first-ks B-frags before the barrier
    const int ks0b = bid & 7;
    bf16x8 pmh[2];
    {
        int half = ks0b >> 2, kk = ks0b & 3;
        #pragma unroll
        for (int n = 0; n < 2; ++n)
            pmh[n] = *(const bf16x8*)(Mh + ((2 * w + n) * 16 + i16) * 256 + half * 128 + kk * 32 + quad * 8);
    }
    __syncthreads();   // phase 2 reads all waves' U rows

    // ---- Phase 2: Z = U(64x256) @ M^T, single-bf16 M, column-split waves:
    // wave w owns channels [32w,+32), all 4 row-blocks -> B reuse = 4 MFMAs.
    f32x4 acc[4][2];   // [row-block rb][col-block n]
    #pragma unroll
    for (int rb = 0; rb < 4; ++rb)
        #pragma unroll
        for (int n = 0; n < 2; ++n) acc[rb][n] = (f32x4){0.f, 0.f, 0.f, 0.f};

    #pragma unroll
    for (int ks = 0; ks < 8; ++ks) {
        int ksr = (ks + bid) & 7;                  // per-block rotation
        int half = ksr >> 2, kk = ksr & 3;
        int base = half << 14;                     // 0 (U-low) or 16384 (U-high)
        int gi = kk * 4 + quad;
        bf16x8 a[4];
        #pragma unroll
        for (int rb = 0; rb < 4; ++rb)
            a[rb] = *(const bf16x8*)(smem + base + AADDR(16 * rb + i16, gi));
        #pragma unroll
        for (int n = 0; n < 2; ++n) {
            bf16x8 bh;
            if (ks == 0) bh = pmh[n];
            else bh = *(const bf16x8*)(Mh + ((2 * w + n) * 16 + i16) * 256 + half * 128 + kk * 32 + quad * 8);
            #pragma unroll
            for (int rb = 0; rb < 4; ++rb)
                acc[rb][n] = __builtin_amdgcn_mfma_f32_16x16x32_bf16(a[rb], bh, acc[rb][n], 0, 0, 0);
        }
    }

    // ---- Epilogue: scale/bias/LeakyReLU, j-contiguous float4 stores
    {
        float* outp = out + (size_t)(bid >> 4) * 131072 + (bid & 15) * 64;
        #pragma unroll
        for (int n = 0; n < 2; ++n) {
            int o = (2 * w + n) * 16 + i16;
            float sc = scale2[o], bi = bias2[o];
            #pragma unroll
            for (int rb = 0; rb < 4; ++rb) {
                int jb = 16 * rb + quad * 4;
                f32x4 a = acc[rb][n];
                float4 r;
                r.x = lrelu(a[0] * sc + bi);
                r.y = lrelu(a[1] * sc + bi);
                r.z = lrelu(a[2] * sc + bi);
                r.w = lrelu(a[3] * sc + bi);
                *(float4*)(outp + (size_t)o * 1024 + jb) = r;
            }
        }
    }
}

// ---------------------------------------------------------------------------
// Fallback (r6, proven 42.4 us): single fused kernel, used if ws_size can't
// hold the 16.8 MB g buffer.
// ---------------------------------------------------------------------------
__global__ __launch_bounds__(256, 4) void fused_kernel(
    const float* __restrict__ x, const float* __restrict__ y,
    const unsigned short* __restrict__ Gh, const unsigned short* __restrict__ Gl,
    const unsigned short* __restrict__ Mh,
    const float* __restrict__ scale2, const float* __restrict__ bias2,
    float* __restrict__ out)
{
    __shared__ __align__(16) unsigned char smem[32768];
    float* gbufF = (float*)(smem + 16384);

    const int tid = threadIdx.x;
    const int w = tid >> 6;
    const int l = tid & 63;
    const int quad = l >> 4;
    const int i16 = l & 15;
    const int bid = blockIdx.x;
    const int b0 = bid * 32;

    union F8 { float4 v[2]; float f[8]; };
    F8 X[2][4];
    #pragma unroll
    for (int pass = 0; pass < 2; ++pass) {
        int b_loc = 8 * w + pass * 4 + quad;
        const float* xb = x + (size_t)(b0 + b_loc) * 512 + i16 * 8;
        #pragma unroll
        for (int t = 0; t < 4; ++t) {
            X[pass][t].v[0] = *(const float4*)(xb + t * 128);
            X[pass][t].v[1] = *(const float4*)(xb + t * 128 + 4);
        }
    }
    const int ks0 = bid & 3;
    bf16x8 pgh[2], pgl[2];
    #pragma unroll
    for (int n = 0; n < 2; ++n) {
        int off = ((2 * w + n) * 16 + i16) * 128 + ks0 * 32 + quad * 8;
        pgh[n] = *(const bf16x8*)(Gh + off);
        pgl[n] = *(const bf16x8*)(Gl + off);
    }

    {
        const float* yb = y + (size_t)b0 * 128;
        #pragma unroll
        for (int it = 0; it < 2; ++it) {
            int j = tid + it * 256;
            int row = j >> 4, gk = j & 15;
            float4 v0 = *(const float4*)(yb + row * 128 + gk * 8);
            float4 v1 = *(const float4*)(yb + row * 128 + gk * 8 + 4);
            float f[8] = {v0.x, v0.y, v0.z, v0.w, v1.x, v1.y, v1.z, v1.w};
            uint32_t hi[4], lo[4];
            #pragma unroll
            for (int e = 0; e < 4; ++e) {
                unsigned short h0 = f2bf(f[2 * e]), h1 = f2bf(f[2 * e + 1]);
                hi[e] = (uint32_t)h0 | ((uint32_t)h1 << 16);
                lo[e] = (uint32_t)f2bf(f[2 * e] - bf2f(h0)) |
                        ((uint32_t)f2bf(f[2 * e + 1] - bf2f(h1)) << 16);
            }
            int addr = AADDR(row, gk);
            *(uint4*)(smem + addr)        = make_uint4(hi[0], hi[1], hi[2], hi[3]);
            *(uint4*)(smem + 8192 + addr) = make_uint4(lo[0], lo[1], lo[2], lo[3]);
        }
    }
    __syncthreads();

    {
        f32x4 accg[2][2];
        #pragma unroll
        for (int rt = 0; rt < 2; ++rt)
            #pragma unroll
            for (int n = 0; n < 2; ++n) accg[rt][n] = (f32x4){0.f, 0.f, 0.f, 0.f};
        #pragma unroll
        for (int ks = 0; ks < 4; ++ks) {
            int ksr = (ks + bid) & 3;
            bf16x8 ah[2], al[2];
            #pragma unroll
            for (int rt = 0; rt < 2; ++rt) {
                int row = 16 * rt + i16;
                int addr = AADDR(row, ksr * 4 + quad);
                ah[rt] = *(const bf16x8*)(smem + addr);
                al[rt] = *(const bf16x8*)(smem + 8192 + addr);
            }
            #pragma unroll
            for (int n = 0; n < 2; ++n) {
                bf16x8 bh, bl;
                if (ks == 0) { bh = pgh[n]; bl = pgl[n]; }
                else {
                    int off = ((2 * w + n) * 16 + i16) * 128 + ksr * 32 + quad * 8;
                    bh = *(const bf16x8*)(Gh + off);
                    bl = *(const bf16x8*)(Gl + off);
                }
                #pragma unroll
                for (int rt = 0; rt < 2; ++rt) {
                    accg[rt][n] = __builtin_amdgcn_mfma_f32_16x16x32_bf16(ah[rt], bh, accg[rt][n], 0, 0, 0);
                    accg[rt][n] = __builtin_amdgcn_mfma_f32_16x16x32_bf16(al[rt], bh, accg[rt][n], 0, 0, 0);
                    accg[rt][n] = __builtin_amdgcn_mfma_f32_16x16x32_bf16(ah[rt], bl, accg[rt][n], 0, 0, 0);
                }
            }
        }
        #pragma unroll
        for (int n = 0; n < 2; ++n) {
            int i = (2 * w + n) * 16 + i16;
            #pragma unroll
            for (int rt = 0; rt < 2; ++rt)
                #pragma unroll
                for (int r = 0; r < 4; ++r)
                    gbufF[(16 * rt + quad * 4 + r) * 128 + i] = accg[rt][n][r];
        }
    }
    __syncthreads();

    #pragma unroll
    for (int pass = 0; pass < 2; ++pass) {
        int b_loc = 8 * w + pass * 4 + quad;
        float4 ga = *(const float4*)(gbufF + b_loc * 128 + i16 * 8);
        float4 gb = *(const float4*)(gbufF + b_loc * 128 + i16 * 8 + 4);
        float p[4];
        #pragma unroll
        for (int t = 0; t < 4; ++t) {
            float4 a = X[pass][t].v[0], b = X[pass][t].v[1];
            p[t] = a.x * ga.x + a.y * ga.y + a.z * ga.z + a.w * ga.w
                 + b.x * gb.x + b.y * gb.y + b.z * gb.z + b.w * gb.w;
        }
        #pragma unroll
        for (int off = 8; off >= 1; off >>= 1) {
            p[0] += __shfl_xor(p[0], off);
            p[1] += __shfl_xor(p[1], off);
            p[2] += __shfl_xor(p[2], off);
            p[3] += __shfl_xor(p[3], off);
        }
        float mx = fmaxf(fmaxf(p[0], p[1]), fmaxf(p[2], p[3]));
        float e0 = __expf(p[0] - mx), e1 = __expf(p[1] - mx);
        float e2 = __expf(p[2] - mx), e3 = __expf(p[3] - mx);
        float inv = 1.f / (e0 + e1 + e2 + e3);
        float w0 = e0 * inv, w1 = e1 * inv, w2 = e2 * inv, w3 = e3 * inv;
        int r0 = 2 * b_loc, r1 = r0 + 1;
        int a0 = AADDR(r0, i16), a1 = AADDR(r1, i16);
        uint32_t eL[4], oL[4], eH[4], oH[4];
        #pragma unroll
        for (int e = 0; e < 4; ++e) {
            int c0 = 2 * e, c1 = 2 * e + 1;
            eL[e] = pack2bf(w0 * X[pass][0].f[c0] + w1 * X[pass][1].f[c0], w0 * X[pass][0].f[c1] + w1 * X[pass][1].f[c1]);
            oL[e] = pack2bf(w0 * X[pass][0].f[c0] - w1 * X[pass][1].f[c0], w0 * X[pass][0].f[c1] - w1 * X[pass][1].f[c1]);
            eH[e] = pack2bf(w2 * X[pass][2].f[c0] + w3 * X[pass][3].f[c0], w2 * X[pass][2].f[c1] + w3 * X[pass][3].f[c1]);
            oH[e] = pack2bf(w2 * X[pass][2].f[c0] - w3 * X[pass][3].f[c0], w2 * X[pass][2].f[c1] - w3 * X[pass][3].f[c1]);
        }
        *(uint4*)(smem + a0)         = make_uint4(eL[0], eL[1], eL[2], eL[3]);
        *(uint4*)(smem + a1)         = make_uint4(oL[0], oL[1], oL[2], oL[3]);
        *(uint4*)(smem + 16384 + a0) = make_uint4(eH[0], eH[1], eH[2], eH[3]);
        *(uint4*)(smem + 16384 + a1) = make_uint4(oH[0], oH[1], oH[2], oH[3]);
    }

    const int ks0b = bid & 7;
    bf16x8 pmh[2];
    {
        int half = ks0b >> 2, kk = ks0b & 3;
        #pragma unroll
        for (int n = 0; n < 2; ++n)
            pmh[n] = *(const bf16x8*)(Mh + ((2 * w + n) * 16 + i16) * 256 + half * 128 + kk * 32 + quad * 8);
    }
    __syncthreads();

    f32x4 acc[4][2];
    #pragma unroll
    for (int rb = 0; rb < 4; ++rb)
        #pragma unroll
        for (int n = 0; n < 2; ++n) acc[rb][n] = (f32x4){0.f, 0.f, 0.f, 0.f};

    #pragma unroll
    for (int ks = 0; ks < 8; ++ks) {
        int ksr = (ks + bid) & 7;
        int half = ksr >> 2, kk = ksr & 3;
        int base = half << 14;
        int gi = kk * 4 + quad;
        bf16x8 a[4];
        #pragma unroll
        for (int rb = 0; rb < 4; ++rb)
            a[rb] = *(const bf16x8*)(smem + base + AADDR(16 * rb + i16, gi));
        #pragma unroll
        for (int n = 0; n < 2; ++n) {
            bf16x8 bh;
            if (ks == 0) bh = pmh[n];
            else bh = *(const bf16x8*)(Mh + ((2 * w + n) * 16 + i16) * 256 + half * 128 + kk * 32 + quad * 8);
            #pragma unroll
            for (int rb = 0; rb < 4; ++rb)
                acc[rb][n] = __builtin_amdgcn_mfma_f32_16x16x32_bf16(a[rb], bh, acc[rb][n], 0, 0, 0);
        }
    }

    {
        float* outp = out + (size_t)(bid >> 4) * 131072 + (bid & 15) * 64;
        #pragma unroll
        for (int n = 0; n < 2; ++n) {
            int o = (2 * w + n) * 16 + i16;
            float sc = scale2[o], bi = bias2[o];
            #pragma unroll
            for (int rb = 0; rb < 4; ++rb) {
                int jb = 16 * rb + quad * 4;
                f32x4 a = acc[rb][n];
                float4 r;
                r.x = lrelu(a[0] * sc + bi);
                r.y = lrelu(a[1] * sc + bi);
                r.z = lrelu(a[2] * sc + bi);
                r.w = lrelu(a[3] * sc + bi);
                *(float4*)(outp + (size_t)o * 1024 + jb) = r;
            }
        }
    }
}

extern "C" void kernel_launch(void* const* d_in, const int* in_sizes, int n_in,
                              void* d_out, int out_size, void* d_ws, size_t ws_size,
                              hipStream_t stream)
{
    (void)in_sizes; (void)n_in; (void)out_size;
    const float* x        = (const float*)d_in[0];
    const float* y        = (const float*)d_in[1];
    const float* Wq       = (const float*)d_in[2];
    const float* Wk       = (const float*)d_in[3];
    const float* Wv       = (const float*)d_in[4];
    const float* conv_w   = (const float*)d_in[5];
    const float* conv_b   = (const float*)d_in[6];
    const float* bn_gamma = (const float*)d_in[7];
    const float* bn_beta  = (const float*)d_in[8];
    const float* bn_mean  = (const float*)d_in[9];
    const float* bn_var   = (const float*)d_in[10];

    unsigned char* ws = (unsigned char*)d_ws;
    unsigned short* Gh = (unsigned short*)(ws);                // 32 KB
    unsigned short* Gl = (unsigned short*)(ws + 32768);        // 32 KB
    unsigned short* Mh = (unsigned short*)(ws + 65536);        // 64 KB
    float* scale2      = (float*)(ws + 131072);                // 512 B
    float* bias2       = (float*)(ws + 131584);                // 512 B
    const size_t G_OFF = 135168;                               // 16B-aligned
    float* gbuf        = (float*)(ws + G_OFF);                 // 16.8 MB
    const size_t need  = G_OFF + (size_t)32768 * 128 * 4;

    hipLaunchKernelGGL(precompute_kernel, dim3(193), dim3(256), 0, stream,
                       Wq, Wk, Wv, conv_w, conv_b, bn_gamma, bn_beta, bn_mean,
                       bn_var, Gh, Gl, Mh, scale2, bias2);
    if (ws_size >= need) {
        hipLaunchKernelGGL(g_kernel, dim3(1024), dim3(256), 0, stream,
                           y, Gh, Gl, gbuf);
        hipLaunchKernelGGL(fused2_kernel, dim3(1024), dim3(256), 0, stream,
                           x, gbuf, Mh, scale2, bias2, (float*)d_out);
    } else {
        hipLaunchKernelGGL(fused_kernel, dim3(1024), dim3(256), 0, stream,
                           x, y, Gh, Gl, Mh, scale2, bias2, (float*)d_out);
    }
}

// Round 4
// 149.487 us; speedup vs baseline: 1.1420x; 1.0454x over previous
//
#include <hip/hip_runtime.h>
#include <stdint.h>

// Problem constants
//  B = 32768 samples, T_X = 4, K = 128, 64 groups x 512, out = (64,128,1,1024) fp32
typedef __attribute__((ext_vector_type(8))) short bf16x8;  // 8 bf16 in 4 VGPRs
typedef __attribute__((ext_vector_type(4))) float f32x4;

__device__ __forceinline__ unsigned short f2bf(float x) {
    union { float f; uint32_t u; } v; v.f = x;
    uint32_t r = v.u + 0x7FFFu + ((v.u >> 16) & 1u);   // RNE
    return (unsigned short)(r >> 16);
}
__device__ __forceinline__ uint32_t pack2bf(float a, float b) {
    return (uint32_t)f2bf(a) | ((uint32_t)f2bf(b) << 16);
}
// v_cvt_pk_bf16_f32: dst.lo = bf16(a), dst.hi = bf16(b), RNE — bit-identical
// to pack2bf but 1 instruction instead of ~9 (T12 recipe; no builtin on gfx950).
__device__ __forceinline__ uint32_t cvtpk(float a, float b) {
    uint32_t r;
    asm("v_cvt_pk_bf16_f32 %0, %1, %2" : "=v"(r) : "v"(a), "v"(b));
    return r;
}
__device__ __forceinline__ float bf2f(uint32_t lo) {
    union { uint32_t u; float f; } v; v.u = lo << 16; return v.f;
}
__device__ __forceinline__ float lrelu(float v) { return v > 0.f ? v : 0.01f * v; }

// ---------------------------------------------------------------------------
// K0: precompute (LDS-tiled small GEMMs, coalesced staging) — unchanged
//   G (split hi/lo bf16): G[i][j] = (1/sqrt(128)) * sum_o Wk[o,i]*Wq[o,j]
//   M (single bf16 RNE):  M[o][c] = inv_sqrt2 * sum_k conv_w[o,(c>>7)*128+k]*Wv[k,c&127]
//   blocks 0..63: G 16x16 tiles; 64..191: M 16x16 tiles; 192: BN constants
// ---------------------------------------------------------------------------
__global__ __launch_bounds__(256) void precompute_kernel(
    const float* __restrict__ Wq, const float* __restrict__ Wk,
    const float* __restrict__ Wv, const float* __restrict__ conv_w,
    const float* __restrict__ conv_b, const float* __restrict__ bn_gamma,
    const float* __restrict__ bn_beta, const float* __restrict__ bn_mean,
    const float* __restrict__ bn_var,
    unsigned short* __restrict__ Gh, unsigned short* __restrict__ Gl,
    unsigned short* __restrict__ Mh,
    float* __restrict__ scale2, float* __restrict__ bias2)
{
    __shared__ float lds0[2176];   // 128x16 pad17 (8704 B) or 16x128 pad132
    __shared__ float lds1[2176];   // 128x16 pad17
    const int tid = threadIdx.x;
    const int bid = blockIdx.x;

    if (bid == 192) {                              // constants
        if (tid < 128) {
            float sc = bn_gamma[tid] * rsqrtf(bn_var[tid] + 1e-5f);
            scale2[tid] = sc;
            bias2[tid]  = (conv_b[tid] - bn_mean[tid]) * sc + bn_beta[tid];
        }
        return;
    }

    if (bid < 64) {                                // ---- G tile (i0, j0)
        int i0 = (bid >> 3) << 4, j0 = (bid & 7) << 4;
        #pragma unroll
        for (int t = 0; t < 8; ++t) {              // stage col-tiles, 64B lines
            int e = tid + t * 256;
            int o = e >> 4, c = e & 15;
            lds0[o * 17 + c] = Wk[o * 128 + i0 + c];
            lds1[o * 17 + c] = Wq[o * 128 + j0 + c];
        }
        __syncthreads();
        int ti = tid >> 4, tj = tid & 15;
        float sum = 0.f;
        #pragma unroll 8
        for (int o = 0; o < 128; ++o) sum += lds0[o * 17 + ti] * lds1[o * 17 + tj];
        float val = sum * 0.08838834764831845f;    // 1/sqrt(128)
        unsigned short h = f2bf(val);
        int idx = (i0 + ti) * 128 + j0 + tj;
        Gh[idx] = h;
        Gl[idx] = f2bf(val - bf2f(h));
    } else {                                       // ---- M tile (o0, c0)
        int rel = bid - 64;
        int o0 = (rel >> 4) << 4, c0 = (rel & 15) << 4;
        int cw0 = (c0 >> 7) << 7, cc0 = c0 & 127;
        #pragma unroll
        for (int t = 0; t < 8; ++t) {
            int e = tid + t * 256;
            int to = e >> 7, k = e & 127;          // conv_w rows: contiguous
            lds0[to * 132 + k] = conv_w[(o0 + to) * 256 + cw0 + k];
            int kk = e >> 4, c = e & 15;           // Wv col-tile
            lds1[kk * 17 + c] = Wv[kk * 128 + cc0 + c];
        }
        __syncthreads();
        int to = tid >> 4, tc = tid & 15;
        float sum = 0.f;
        #pragma unroll 8
        for (int k = 0; k < 128; ++k) sum += lds0[to * 132 + k] * lds1[k * 17 + tc];
        Mh[(o0 + to) * 256 + c0 + tc] = f2bf(sum * 0.7071067811865476f);
    }
}

// ---------------------------------------------------------------------------
// K1 (r10): single fused kernel, 32 samples/block, 1024 blocks, 32 KB LDS.
// r10 vs r6/r9: (a) g_kernel RE-FUSED (r9 post-mortem: g_kernel cost ~13 us
// + 33.6 MB round-trip; the split was a net loss). (b) VMEM issue order =
// CONSUMPTION order: y(2) -> ALL 16 G fragments -> X(16). In-order vmcnt
// retirement means phase 0a waits only for y, 0b waits only for y+G, and the
// x bulk drains under 0a/0b compute. r6's bug: X issued first AND ks>=1 G
// loads issued in-loop (behind X) -> every 0b step drained the whole queue.
// (c) phase-1 bf16 packs via v_cvt_pk_bf16_f32 (1 inst vs ~9, same RNE).
// (d) amdgpu_waves_per_eu(3): 170-reg tier fits y(16)+G(64)+X(64)+temps
// without spill; 3 blocks/CU + 256-block trailing generation gives stagger.
// LDS overlays (proven r6 invariants):
//   [0,16K)  phase0: y bf16 hi [0,8K) + lo [8K,16K) -> phase1+: U-low bf16
//   [16K,32K) phase0b out: gbuf fp32 (32x128)       -> phase1+: U-high bf16
// (thread reads gbuf row b_loc then writes U-high rows 2*b_loc..+1 = same
// bytes, same thread, program-ordered => no hazard.)
// ---------------------------------------------------------------------------
#define AADDR(row, gi)   (((row) << 8) + ((((gi) ^ ((row) & 7))) << 4))

__global__ __launch_bounds__(256)
__attribute__((amdgpu_waves_per_eu(3)))
void fused_kernel(
    const float* __restrict__ x, const float* __restrict__ y,
    const unsigned short* __restrict__ Gh, const unsigned short* __restrict__ Gl,
    const unsigned short* __restrict__ Mh,
    const float* __restrict__ scale2, const float* __restrict__ bias2,
    float* __restrict__ out)
{
    __shared__ __align__(16) unsigned char smem[32768];
    float* gbufF = (float*)(smem + 16384);

    const int tid = threadIdx.x;
    const int w = tid >> 6;          // wave 0..3
    const int l = tid & 63;          // lane
    const int quad = l >> 4;
    const int i16 = l & 15;
    const int bid = blockIdx.x;
    const int b0 = bid * 32;

    // ---- VMEM queue, consumption order ----------------------------------
    // (1) y: consumed by phase 0a (pack to LDS)
    float4 yv0[2], yv1[2];
    int rowA[2], gkA[2];
    #pragma unroll
    for (int it = 0; it < 2; ++it) {
        int j = tid + it * 256;                // 512 granules: 32 rows x 16
        rowA[it] = j >> 4; gkA[it] = j & 15;
        const float* yb = y + (size_t)(b0 + rowA[it]) * 128 + gkA[it] * 8;
        yv0[it] = *(const float4*)(yb);
        yv1[it] = *(const float4*)(yb + 4);
    }
    // (2) ALL G B-fragments for phase 0b (4 ks x 2 col-blocks, hi+lo)
    bf16x8 pgh[4][2], pgl[4][2];
    #pragma unroll
    for (int ks = 0; ks < 4; ++ks) {
        int ksr = (ks + bid) & 3;              // per-block rotation
        #pragma unroll
        for (int n = 0; n < 2; ++n) {
            int off = ((2 * w + n) * 16 + i16) * 128 + ksr * 32 + quad * 8;
            pgh[ks][n] = *(const bf16x8*)(Gh + off);
            pgl[ks][n] = *(const bf16x8*)(Gl + off);
        }
    }
    // (3) x bulk: consumed by phase 1 (drains under 0a/0b compute)
    union F8 { float4 v[2]; float f[8]; };
    F8 X[2][4];                      // [pass][t], 64 VGPRs
    #pragma unroll
    for (int pass = 0; pass < 2; ++pass) {
        int b_loc = 8 * w + pass * 4 + quad;
        const float* xb = x + (size_t)(b0 + b_loc) * 512 + i16 * 8;
        #pragma unroll
        for (int t = 0; t < 4; ++t) {
            X[pass][t].v[0] = *(const float4*)(xb + t * 128);
            X[pass][t].v[1] = *(const float4*)(xb + t * 128 + 4);
        }
    }

    // ---- Phase 0a: stage y as split bf16 hi/lo in MFMA-A-frag layout.
    #pragma unroll
    for (int it = 0; it < 2; ++it) {
        float f[8] = {yv0[it].x, yv0[it].y, yv0[it].z, yv0[it].w,
                      yv1[it].x, yv1[it].y, yv1[it].z, yv1[it].w};
        uint32_t hi[4], lo[4];
        #pragma unroll
        for (int e = 0; e < 4; ++e) {
            unsigned short h0 = f2bf(f[2 * e]), h1 = f2bf(f[2 * e + 1]);
            hi[e] = (uint32_t)h0 | ((uint32_t)h1 << 16);
            lo[e] = (uint32_t)f2bf(f[2 * e] - bf2f(h0)) |
                    ((uint32_t)f2bf(f[2 * e + 1] - bf2f(h1)) << 16);
        }
        int addr = AADDR(rowA[it], gkA[it]);   // rows 0..31 -> [0,8K)
        *(uint4*)(smem + addr)        = make_uint4(hi[0], hi[1], hi[2], hi[3]);
        *(uint4*)(smem + 8192 + addr) = make_uint4(lo[0], lo[1], lo[2], lo[3]);
    }
    __syncthreads();

    // ---- Phase 0b: g = Y @ G^T (split precision), column-split waves.
    // All B-fragments already in registers — no VMEM after this point until
    // the (already-issued) X loads are consumed.
    {
        f32x4 accg[2][2];    // [sample-tile rt][col-block n]
        #pragma unroll
        for (int rt = 0; rt < 2; ++rt)
            #pragma unroll
            for (int n = 0; n < 2; ++n) accg[rt][n] = (f32x4){0.f, 0.f, 0.f, 0.f};
        #pragma unroll
        for (int ks = 0; ks < 4; ++ks) {
            int ksr = (ks + bid) & 3;
            bf16x8 ah[2], al[2];
            #pragma unroll
            for (int rt = 0; rt < 2; ++rt) {
                int row = 16 * rt + i16;
                int addr = AADDR(row, ksr * 4 + quad);
                ah[rt] = *(const bf16x8*)(smem + addr);
                al[rt] = *(const bf16x8*)(smem + 8192 + addr);
            }
            #pragma unroll
            for (int n = 0; n < 2; ++n) {
                #pragma unroll
                for (int rt = 0; rt < 2; ++rt) {
                    accg[rt][n] = __builtin_amdgcn_mfma_f32_16x16x32_bf16(ah[rt], pgh[ks][n], accg[rt][n], 0, 0, 0);
                    accg[rt][n] = __builtin_amdgcn_mfma_f32_16x16x32_bf16(al[rt], pgh[ks][n], accg[rt][n], 0, 0, 0);
                    accg[rt][n] = __builtin_amdgcn_mfma_f32_16x16x32_bf16(ah[rt], pgl[ks][n], accg[rt][n], 0, 0, 0);
                }
            }
        }
        // C-frag: col = i16 (i offset), row = quad*4+r (sample) -> gbuf fp32
        #pragma unroll
        for (int n = 0; n < 2; ++n) {
            int i = (2 * w + n) * 16 + i16;
            #pragma unroll
            for (int rt = 0; rt < 2; ++rt)
                #pragma unroll
                for (int r = 0; r < 4; ++r)
                    gbufF[(16 * rt + quad * 4 + r) * 128 + i] = accg[rt][n][r];
        }
    }
    __syncthreads();   // g rows assembled from all four waves' col-blocks

    // ---- Phase 1: dots + softmax + U build. One sample per (wave,pass,quad).
    // x arrives in issue order: pass-0 X completes first, pipelines with
    // pass-0 compute while pass-1 X is still in flight.
    #pragma unroll
    for (int pass = 0; pass < 2; ++pass) {
        int b_loc = 8 * w + pass * 4 + quad;
        float4 ga = *(const float4*)(gbufF + b_loc * 128 + i16 * 8);
        float4 gb = *(const float4*)(gbufF + b_loc * 128 + i16 * 8 + 4);
        float p[4];
        #pragma unroll
        for (int t = 0; t < 4; ++t) {
            float4 a = X[pass][t].v[0], b = X[pass][t].v[1];
            p[t] = a.x * ga.x + a.y * ga.y + a.z * ga.z + a.w * ga.w
                 + b.x * gb.x + b.y * gb.y + b.z * gb.z + b.w * gb.w;
        }
        #pragma unroll
        for (int off = 8; off >= 1; off >>= 1) {
            p[0] += __shfl_xor(p[0], off);
            p[1] += __shfl_xor(p[1], off);
            p[2] += __shfl_xor(p[2], off);
            p[3] += __shfl_xor(p[3], off);
        }
        float mx = fmaxf(fmaxf(p[0], p[1]), fmaxf(p[2], p[3]));
        float e0 = __expf(p[0] - mx), e1 = __expf(p[1] - mx);
        float e2 = __expf(p[2] - mx), e3 = __expf(p[3] - mx);
        float inv = 1.f / (e0 + e1 + e2 + e3);
        float w0 = e0 * inv, w1 = e1 * inv, w2 = e2 * inv, w3 = e3 * inv;
        int r0 = 2 * b_loc, r1 = r0 + 1;
        int a0 = AADDR(r0, i16), a1 = AADDR(r1, i16);
        uint32_t eL[4], oL[4], eH[4], oH[4];
        #pragma unroll
        for (int e = 0; e < 4; ++e) {
            int c0 = 2 * e, c1 = 2 * e + 1;
            eL[e] = cvtpk(w0 * X[pass][0].f[c0] + w1 * X[pass][1].f[c0], w0 * X[pass][0].f[c1] + w1 * X[pass][1].f[c1]);
            oL[e] = cvtpk(w0 * X[pass][0].f[c0] - w1 * X[pass][1].f[c0], w0 * X[pass][0].f[c1] - w1 * X[pass][1].f[c1]);
            eH[e] = cvtpk(w2 * X[pass][2].f[c0] + w3 * X[pass][3].f[c0], w2 * X[pass][2].f[c1] + w3 * X[pass][3].f[c1]);
            oH[e] = cvtpk(w2 * X[pass][2].f[c0] - w3 * X[pass][3].f[c0], w2 * X[pass][2].f[c1] - w3 * X[pass][3].f[c1]);
        }
        *(uint4*)(smem + a0)         = make_uint4(eL[0], eL[1], eL[2], eL[3]);
        *(uint4*)(smem + a1)         = make_uint4(oL[0], oL[1], oL[2], oL[3]);
        *(uint4*)(smem + 16384 + a0) = make_uint4(eH[0], eH[1], eH[2], eH[3]);
        *(uint4*)(smem + 16384 + a1) = make_uint4(oH[0], oH[1], oH[2], oH[3]);
    }

    // Prefetch phase-2 first-ks B-frags before the barrier (L2-resident)
    const int ks0b = bid & 7;
    bf16x8 pmh[2];
    {
        int half = ks0b >> 2, kk = ks0b & 3;
        #pragma unroll
        for (int n = 0; n < 2; ++n)
            pmh[n] = *(const bf16x8*)(Mh + ((2 * w + n) * 16 + i16) * 256 + half * 128 + kk * 32 + quad * 8);
    }
    __syncthreads();   // phase 2 reads all waves' U rows

    // ---- Phase 2: Z = U(64x256) @ M^T, single-bf16 M, column-split waves:
    // wave w owns channels [32w,+32), all 4 row-blocks -> B reuse = 4 MFMAs.
    f32x4 acc[4][2];   // [row-block rb][col-block n]
    #pragma unroll
    for (int rb = 0; rb < 4; ++rb)
        #pragma unroll
        for (int n = 0; n < 2; ++n) acc[rb][n] = (f32x4){0.f, 0.f, 0.f, 0.f};

    #pragma unroll
    for (int ks = 0; ks < 8; ++ks) {
        int ksr = (ks + bid) & 7;                  // per-block rotation
        int half = ksr >> 2, kk = ksr & 3;
        int base = half << 14;                     // 0 (U-low) or 16384 (U-high)
        int gi = kk * 4 + quad;
        bf16x8 a[4];
        #pragma unroll
        for (int rb = 0; rb < 4; ++rb)
            a[rb] = *(const bf16x8*)(smem + base + AADDR(16 * rb + i16, gi));
        #pragma unroll
        for (int n = 0; n < 2; ++n) {
            bf16x8 bh;
            if (ks == 0) bh = pmh[n];
            else bh = *(const bf16x8*)(Mh + ((2 * w + n) * 16 + i16) * 256 + half * 128 + kk * 32 + quad * 8);
            #pragma unroll
            for (int rb = 0; rb < 4; ++rb)
                acc[rb][n] = __builtin_amdgcn_mfma_f32_16x16x32_bf16(a[rb], bh, acc[rb][n], 0, 0, 0);
        }
    }

    // ---- Epilogue: scale/bias/LeakyReLU, j-contiguous float4 stores
    {
        float* outp = out + (size_t)(bid >> 4) * 131072 + (bid & 15) * 64;
        #pragma unroll
        for (int n = 0; n < 2; ++n) {
            int o = (2 * w + n) * 16 + i16;
            float sc = scale2[o], bi = bias2[o];
            #pragma unroll
            for (int rb = 0; rb < 4; ++rb) {
                int jb = 16 * rb + quad * 4;
                f32x4 a = acc[rb][n];
                float4 r;
                r.x = lrelu(a[0] * sc + bi);
                r.y = lrelu(a[1] * sc + bi);
                r.z = lrelu(a[2] * sc + bi);
                r.w = lrelu(a[3] * sc + bi);
                *(float4*)(outp + (size_t)o * 1024 + jb) = r;
            }
        }
    }
}

extern "C" void kernel_launch(void* const* d_in, const int* in_sizes, int n_in,
                              void* d_out, int out_size, void* d_ws, size_t ws_size,
                              hipStream_t stream)
{
    (void)in_sizes; (void)n_in; (void)out_size; (void)ws_size;
    const float* x        = (const float*)d_in[0];
    const float* y        = (const float*)d_in[1];
    const float* Wq       = (const float*)d_in[2];
    const float* Wk       = (const float*)d_in[3];
    const float* Wv       = (const float*)d_in[4];
    const float* conv_w   = (const float*)d_in[5];
    const float* conv_b   = (const float*)d_in[6];
    const float* bn_gamma = (const float*)d_in[7];
    const float* bn_beta  = (const float*)d_in[8];
    const float* bn_mean  = (const float*)d_in[9];
    const float* bn_var   = (const float*)d_in[10];

    unsigned char* ws = (unsigned char*)d_ws;
    unsigned short* Gh = (unsigned short*)(ws);                // 32 KB
    unsigned short* Gl = (unsigned short*)(ws + 32768);        // 32 KB
    unsigned short* Mh = (unsigned short*)(ws + 65536);        // 64 KB
    float* scale2      = (float*)(ws + 131072);                // 512 B
    float* bias2       = (float*)(ws + 131584);                // 512 B

    hipLaunchKernelGGL(precompute_kernel, dim3(193), dim3(256), 0, stream,
                       Wq, Wk, Wv, conv_w, conv_b, bn_gamma, bn_beta, bn_mean,
                       bn_var, Gh, Gl, Mh, scale2, bias2);
    hipLaunchKernelGGL(fused_kernel, dim3(1024), dim3(256), 0, stream,
                       x, y, Gh, Gl, Mh, scale2, bias2, (float*)d_out);
}